// Round 5
// baseline (169.494 us; speedup 1.0000x reference)
//
#include <hip/hip_runtime.h>
#include <hip/hip_bf16.h>

// out[b,o] = sum_i x[b,i]*w[o,i] + bias[o]; M=4096, N=2048, K=2048, fp32 io.
// R11: revert R10's fusion (regressed 42->94us: doubling FETCH doubled time).
// Evidence across R6/R8/R9/R10: gemm time tracks FETCH_SIZE at ~0.8-1.0 TB/s
// effective fetch rate regardless of schedule/occupancy/LDS traffic =>
// K-loop is fetch-path-bound. This round: restore verified R9 pipeline and
// fix the one clear serial tail -- the epilogue. Previously ks=1 dumped all
// 32 float4 to LDS and idled while ks=0 alone issued 128 scalar stores.
// Now each wave dumps the half it won't finalize (disjoint 64KB LDS regions)
// and both waves reduce+store 4 rows each: store issue halved, both waves
// drive HBM concurrently. K-loop/staging byte-identical to R9 (passed).

#define M_DIM 4096
#define N_DIM 2048
#define K_DIM 2048
#define BM 256
#define BN 128
#define BK 64
#define NT (K_DIM / BK)   // 32 K-tiles
#define ASZ (BM * BK)     // 16384 ushort = 32 KB
#define BSZ (BN * BK)     // 8192 ushort = 16 KB

typedef unsigned short ushort_t;
typedef __attribute__((ext_vector_type(8))) short short8;      // 8 bf16 (A/B frag)
typedef __attribute__((ext_vector_type(4))) float float4v;     // C/D frag
typedef __attribute__((ext_vector_type(8))) unsigned short ushort8;

// ---------------- fp32 -> bf16 (RNE), x and w fused in one launch ----------------
__device__ __forceinline__ unsigned short f2bf_rne(float f) {
    unsigned int u = __builtin_bit_cast(unsigned int, f);
    u += 0x7FFFu + ((u >> 16) & 1u);
    return (unsigned short)(u >> 16);
}

__global__ void __launch_bounds__(256) cvt_both(const float* __restrict__ x,
                                                const float* __restrict__ w,
                                                ushort8* __restrict__ ws8,
                                                int xN8, int totN8) {
    int idx = blockIdx.x * 256 + threadIdx.x;
    if (idx >= totN8) return;
    const float4v* in4 = (idx < xN8) ? (const float4v*)x + (size_t)idx * 2
                                     : (const float4v*)w + (size_t)(idx - xN8) * 2;
    float4v a = in4[0];
    float4v b = in4[1];
    ushort8 r;
    r[0] = f2bf_rne(a[0]); r[1] = f2bf_rne(a[1]);
    r[2] = f2bf_rne(a[2]); r[3] = f2bf_rne(a[3]);
    r[4] = f2bf_rne(b[0]); r[5] = f2bf_rne(b[1]);
    r[6] = f2bf_rne(b[2]); r[7] = f2bf_rne(b[3]);
    ws8[idx] = r;
}

// ---------------- async global -> LDS (16B per lane; dest = base + lane*16) ----
__device__ __forceinline__ void async_load16(const void* g, void* l) {
    __builtin_amdgcn_global_load_lds(
        (const __attribute__((address_space(1))) void*)(g),
        (__attribute__((address_space(3))) void*)(l), 16, 0, 0);
}

// ---------------- bf16 MFMA GEMM, C = Xb * Wb^T + bias ----------------
// Xb: [M,K] bf16 row-major, Wb: [N,K] bf16 row-major.
// Block: 256x128 tile, 512 threads = 8 waves = 4 positions x 2 K-slices.
__global__ void __launch_bounds__(512, 2)
gemm_bf16_ks(const ushort_t* __restrict__ xb,
             const ushort_t* __restrict__ wb,
             const float* __restrict__ bias,
             float* __restrict__ out) {
    __shared__ ushort_t lds[3 * (ASZ + BSZ)];   // 144 KB total
    ushort_t* ldsA = lds;                       // 3 x 32 KB rotating A tiles
    ushort_t* ldsB = lds + 3 * ASZ;             // 3 x 16 KB rotating B tiles

    const int tid  = threadIdx.x;
    const int wave = tid >> 6;
    const int lane = tid & 63;
    const int quad = lane >> 4;    // 0..3
    const int lrow = lane & 15;    // 0..15

    // XCD-aware swizzle: 256 blocks, 8 XCDs, nwg%8==0 -> simple bijection.
    const int swzb = ((int)blockIdx.x & 7) * 32 + ((int)blockIdx.x >> 3);
    const int rowBase = (swzb >> 4) * BM;   // 16 M-blocks
    const int colBase = (swzb & 15) * BN;   // 16 N-blocks

    const int pos  = wave & 3;      // tile position: 2(row) x 2(col)
    const int ks   = wave >> 2;     // K-slice of each BK=64 tile: 0 -> K[0,32), 1 -> K[32,64)
    const int posR = (pos >> 1) * 128;   // 0 or 128
    const int posC = (pos & 1) * 64;     // 0 or 64

    // ---- staging: rows are 128B = 8 chunks of 16B. One instr = 512 lanes x 16B
    // = 64 rows. Linear LDS dest: row r slot s=(tid&7) holds global chunk
    // q = s ^ (r&7)  (pre-swizzled source, involution matches read side). ----
    const int srow   = tid >> 3;                       // 0..63 within instr
    const int schunk = (tid & 7) ^ (srow & 7);
    const ushort_t* gA[4];
    const ushort_t* gB[2];
#pragma unroll
    for (int j = 0; j < 4; j++)
        gA[j] = xb + (size_t)(rowBase + 64 * j + srow) * K_DIM + schunk * 8;
#pragma unroll
    for (int j = 0; j < 2; j++)
        gB[j] = wb + (size_t)(colBase + 64 * j + srow) * K_DIM + schunk * 8;

    const int ldsw = wave * 512;   // ushort offset: wave-uniform base for gload_lds

    // ---- fragment read swizzle: chunk c = ks*4+quad at slot c ^ (lrow&7);
    // ushort offset = slot*8. posR/posC/mi*16 are all 0 mod 8 -> parity = lrow. ----
    const int swzr = ((quad ^ (lrow & 7)) * 8) ^ (ks * 32);

    float4v acc[8][4] = {};   // 128x64 per-wave tile (over this wave's K-half)

    // ---- prologue: stage tiles 0 (buf0) and 1 (buf1); 12 loads in flight ----
#pragma unroll
    for (int j = 0; j < 4; j++) async_load16(gA[j], ldsA + j * 4096 + ldsw);
#pragma unroll
    for (int j = 0; j < 2; j++) async_load16(gB[j], ldsB + j * 4096 + ldsw);
#pragma unroll
    for (int j = 0; j < 4; j++) async_load16(gA[j] + BK, ldsA + ASZ + j * 4096 + ldsw);
#pragma unroll
    for (int j = 0; j < 2; j++) async_load16(gB[j] + BK, ldsB + BSZ + j * 4096 + ldsw);
#pragma unroll
    for (int j = 0; j < 4; j++) gA[j] += 2 * BK;
#pragma unroll
    for (int j = 0; j < 2; j++) gB[j] += 2 * BK;
    asm volatile("s_waitcnt vmcnt(6)" ::: "memory");   // tile 0 landed
    __builtin_amdgcn_s_barrier();

    int cur = 0;
    for (int t = 0; t < NT; ++t) {
        const ushort_t* aT = ldsA + cur * ASZ + (posR + lrow) * BK;
        const ushort_t* bT = ldsB + cur * BSZ + (posC + lrow) * BK;
        int nb = cur + 2; if (nb >= 3) nb -= 3;        // buf for tile t+2
        ushort_t* sA = ldsA + nb * ASZ;
        ushort_t* sB = ldsB + nb * BSZ;
        const bool stg = (t + 2 < NT);

        // ======== phase 0: A-rows mi 0..3 ========
        short8 af[4], bf[4];
#pragma unroll
        for (int mi = 0; mi < 4; mi++) af[mi] = *(const short8*)(aT + mi * 1024 + swzr);
#pragma unroll
        for (int ni = 0; ni < 4; ni++) bf[ni] = *(const short8*)(bT + ni * 1024 + swzr);
        if (stg) {
#pragma unroll
            for (int j = 0; j < 3; j++) async_load16(gA[j], sA + j * 4096 + ldsw);
        }
        __builtin_amdgcn_s_barrier();
        __builtin_amdgcn_s_setprio(1);
#pragma unroll
        for (int mi = 0; mi < 4; mi++)
#pragma unroll
            for (int ni = 0; ni < 4; ni++)
                acc[mi][ni] = __builtin_amdgcn_mfma_f32_16x16x32_bf16(
                    af[mi], bf[ni], acc[mi][ni], 0, 0, 0);
        __builtin_amdgcn_s_setprio(0);
        __builtin_amdgcn_s_barrier();

        // ======== phase 1: A-rows mi 4..7 (bf reused) ========
        short8 ag[4];
#pragma unroll
        for (int mi = 0; mi < 4; mi++) ag[mi] = *(const short8*)(aT + (mi + 4) * 1024 + swzr);
        if (stg) {
            async_load16(gA[3], sA + 3 * 4096 + ldsw);
#pragma unroll
            for (int j = 0; j < 2; j++) async_load16(gB[j], sB + j * 4096 + ldsw);
#pragma unroll
            for (int j = 0; j < 4; j++) gA[j] += BK;
#pragma unroll
            for (int j = 0; j < 2; j++) gB[j] += BK;
        }
        __builtin_amdgcn_s_barrier();
        __builtin_amdgcn_s_setprio(1);
#pragma unroll
        for (int mi = 0; mi < 4; mi++)
#pragma unroll
            for (int ni = 0; ni < 4; ni++)
                acc[mi + 4][ni] = __builtin_amdgcn_mfma_f32_16x16x32_bf16(
                    ag[mi], bf[ni], acc[mi + 4][ni], 0, 0, 0);
        __builtin_amdgcn_s_setprio(0);

        // ---- K-tile boundary: counted wait. Outstanding = t+1's 6 (oldest)
        // + t+2's 6 (just issued) -> vmcnt(6) keeps t+2 in flight. ----
        if (stg) {
            asm volatile("s_waitcnt vmcnt(6)" ::: "memory");
        } else if (t + 1 < NT) {
            asm volatile("s_waitcnt vmcnt(0)" ::: "memory");
        }
        __builtin_amdgcn_s_barrier();
        cur++; if (cur == 3) cur = 0;
    }

    // ---- epilogue (R11): split reduce+store across both ks waves.
    // acc frag layout (harness-verified): col = lane&15, row = quad*4 + reg.
    // Each wave dumps the half it will NOT finalize:
    //   ks=1 dumps acc[0..3] into region 1; ks=0 dumps acc[4..7] into region 0.
    // Then ks=0 finalizes rows mi 0..3 (reads region 1), ks=1 finalizes
    // mi 4..7 (reads region 0). Regions: ks*16384 + pos*4096 floats
    // (2 x 64 KB = 128 KB <= 144 KB LDS). ----
    float* fl = (float*)lds;
    __syncthreads();   // all staged-tile reads done; drains lgkm + vm
    {
        const int dumpBase = ks * 16384 + pos * 4096;   // float units
        const int moff = ks ? 0 : 4;   // ks=1 dumps mi 0..3; ks=0 dumps mi 4..7
#pragma unroll
        for (int mi = 0; mi < 4; mi++)
#pragma unroll
            for (int ni = 0; ni < 4; ni++)
                *(float4v*)(fl + dumpBase + (mi * 4 + ni) * 256 + lane * 4) =
                    acc[mi + moff][ni];
    }
    __syncthreads();
    {
        const int rdBase = (ks ^ 1) * 16384 + pos * 4096;
        const int moff = ks ? 4 : 0;   // ks=0 finalizes mi 0..3; ks=1 -> mi 4..7
#pragma unroll
        for (int ni = 0; ni < 4; ni++) {
            const int col = colBase + posC + ni * 16 + lrow;
            const float bv = bias[col];
#pragma unroll
            for (int mi = 0; mi < 4; mi++) {
                const int row0 = rowBase + posR + (mi + moff) * 16 + quad * 4;
                float4v p = *(const float4v*)(fl + rdBase + (mi * 4 + ni) * 256 + lane * 4);
                float4v v = acc[mi + moff][ni] + p;
#pragma unroll
                for (int i = 0; i < 4; i++)
                    out[(size_t)(row0 + i) * N_DIM + col] = v[i] + bv;
            }
        }
    }
}

// ---------------- fallback (ws too small): fp32 naive ----------------
__global__ void __launch_bounds__(256) linear_naive(const float* __restrict__ x,
                                                    const float* __restrict__ w,
                                                    const float* __restrict__ bias,
                                                    float* __restrict__ out) {
    __shared__ float xs[K_DIM];
    const int b = blockIdx.y;
    const int o = blockIdx.x * 256 + threadIdx.x;
    for (int k = threadIdx.x; k < K_DIM; k += 256)
        xs[k] = x[(long long)b * K_DIM + k];
    __syncthreads();
    const float4v* wr = (const float4v*)(w + (long long)o * K_DIM);
    float s = 0.f;
    for (int k4 = 0; k4 < K_DIM / 4; k4++) {
        float4v wv = wr[k4];
        float4v xv = *(const float4v*)&xs[k4 * 4];
        s += xv[0] * wv[0] + xv[1] * wv[1] + xv[2] * wv[2] + xv[3] * wv[3];
    }
    out[(long long)b * N_DIM + o] = s + bias[o];
}

extern "C" void kernel_launch(void* const* d_in, const int* in_sizes, int n_in,
                              void* d_out, int out_size, void* d_ws, size_t ws_size,
                              hipStream_t stream) {
    const float* x    = (const float*)d_in[0];   // [4096, 2048]
    const float* w    = (const float*)d_in[1];   // [2048, 2048]
    const float* bias = (const float*)d_in[2];   // [2048]
    float* out = (float*)d_out;                  // [4096, 2048]

    const size_t xElems = (size_t)M_DIM * K_DIM;   // 8388608
    const size_t wElems = (size_t)N_DIM * K_DIM;   // 4194304
    const size_t need = (xElems + wElems) * sizeof(ushort_t);  // ~25.2 MB

    if (ws_size >= need) {
        ushort_t* xb = (ushort_t*)d_ws;
        ushort_t* wb = xb + xElems;
        const int xN8 = (int)(xElems / 8);
        const int totN8 = (int)((xElems + wElems) / 8);
        cvt_both<<<(totN8 + 255) / 256, 256, 0, stream>>>(x, w, (ushort8*)d_ws, xN8, totN8);
        gemm_bf16_ks<<<(M_DIM / BM) * (N_DIM / BN), 512, 0, stream>>>(xb, wb, bias, out);
    } else {
        dim3 grid(N_DIM / 256, M_DIM);
        linear_naive<<<grid, 256, 0, stream>>>(x, w, bias, out);
    }
}

// Round 6
// 130.311 us; speedup vs baseline: 1.3007x; 1.3007x over previous
//
#include <hip/hip_runtime.h>
#include <hip/hip_bf16.h>

// out[b,o] = sum_i x[b,i]*w[o,i] + bias[o]; M=4096, N=2048, K=2048, fp32 io.
// R12: re-anchor. R10 (fused cvt) and R11 (split epilogue) both regressed;
// revert to the session-best round-0 kernel (130.5us verified) VERBATIM,
// plus exactly one isolated, zero-risk change: XCD-aware block swizzle.
// Mechanism: 512 blocks, default round-robin puts the 16 blocks sharing an
// A-panel (bm) on 8 different XCDs -> 8x L3 re-fetch of every A-panel.
// swzb = (bid&7)*64 + bid>>3 (bijective, 512%8==0) gives each XCD 64
// consecutive tiles = 4 full bm-groups: A-panel sharers all on one XCD
// (L2 hits), B-panel gets 4 co-XCD sharers. Targets the measured bottleneck
// (fetch path: gemm runs ~1 TB/s effective fetch, nothing else saturated).
// Everything else byte-identical to round-0: 512thr, 8 waves x 64x32
// wave-tile, BK=128, 2 blocks/CU, chunk-XOR swizzled LDS, global_load_lds.

#define M_DIM 4096
#define N_DIM 2048
#define K_DIM 2048
#define BK 128

typedef unsigned short ushort_t;
typedef __attribute__((ext_vector_type(8))) short short8;      // 8 bf16 (A/B frag)
typedef __attribute__((ext_vector_type(4))) float float4v;     // C/D frag
typedef __attribute__((ext_vector_type(8))) unsigned short ushort8;

// ---------------- fp32 -> bf16 (RNE), x and w fused in one launch ----------------
__device__ __forceinline__ unsigned short f2bf_rne(float f) {
    unsigned int u = __builtin_bit_cast(unsigned int, f);
    u += 0x7FFFu + ((u >> 16) & 1u);
    return (unsigned short)(u >> 16);
}

__global__ void __launch_bounds__(256) cvt_both(const float* __restrict__ x,
                                                const float* __restrict__ w,
                                                ushort8* __restrict__ ws8,
                                                int xN8, int totN8) {
    int idx = blockIdx.x * 256 + threadIdx.x;
    if (idx >= totN8) return;
    const float4v* in4 = (idx < xN8) ? (const float4v*)x + (size_t)idx * 2
                                     : (const float4v*)w + (size_t)(idx - xN8) * 2;
    float4v a = in4[0];
    float4v b = in4[1];
    ushort8 r;
    r[0] = f2bf_rne(a[0]); r[1] = f2bf_rne(a[1]);
    r[2] = f2bf_rne(a[2]); r[3] = f2bf_rne(a[3]);
    r[4] = f2bf_rne(b[0]); r[5] = f2bf_rne(b[1]);
    r[6] = f2bf_rne(b[2]); r[7] = f2bf_rne(b[3]);
    ws8[idx] = r;
}

// ---------------- async global -> LDS (16B per lane; dest = base + lane*16) ----
__device__ __forceinline__ void async_load16(const void* g, void* l) {
    __builtin_amdgcn_global_load_lds(
        (const __attribute__((address_space(1))) void*)(g),
        (__attribute__((address_space(3))) void*)(l), 16, 0, 0);
}

// ---------------- bf16 MFMA GEMM, C = Xb * Wb^T + bias ----------------
// Xb: [M,K] bf16 row-major, Wb: [N,K] bf16 row-major.
// Block: 128x128 tile, 512 threads = 8 waves in 2(row) x 4(col); wave-tile 64x32.
__global__ void __launch_bounds__(512) gemm_bf16(const ushort_t* __restrict__ xb,
                                                 const ushort_t* __restrict__ wb,
                                                 const float* __restrict__ bias,
                                                 float* __restrict__ out) {
    __shared__ ushort_t ldsA[128 * BK];   // 32 KB
    __shared__ ushort_t ldsB[128 * BK];   // 32 KB

    const int tid  = threadIdx.x;
    const int wave = tid >> 6;
    const int lane = tid & 63;
    const int quad = lane >> 4;    // 0..3
    const int lrow = lane & 15;    // 0..15

    // R12: XCD-aware swizzle. 512 blocks, 8 XCDs, 512%8==0 -> bijective.
    // XCD x owns swzb in [x*64, x*64+64): 4 full bm-groups per XCD, so all
    // 16 sharers of an A-panel are co-XCD (L2 reuse instead of 8x L3 fetch).
    const int swzb = ((int)blockIdx.x & 7) * 64 + ((int)blockIdx.x >> 3);
    const int bm = swzb >> 4;    // 0..31
    const int bn = swzb & 15;    // 0..15
    const int rowBase = bm * 128;
    const int colBase = bn * 128;

    const int waveR = (wave >> 2) * 64;   // 0 or 64
    const int waveC = (wave & 3) * 32;    // 0,32,64,96

    // ---- staging: waves 0-3 stage A rows sgrp*32..+31, waves 4-7 stage B ----
    // Rows are 256B = 16 chunks of 16B; one instr covers 4 rows.
    // HW places lane L at row_local L>>4, position L&15. Stored chunk at
    // position p of row r is p ^ (r&15), so instr j (rows R0+4j..+3) lane L
    // fetches global chunk q = (L&15) ^ (L>>4) ^ ((4j)&15).
    const int  sgrp = wave & 3;
    const bool isB  = wave >= 4;
    const int  R0   = sgrp * 32;
    const int  rowl = lane >> 4;          // 0..3
    const int  qb   = (lane & 15) ^ rowl;
    const ushort_t* src = isB ? wb + (long long)colBase * K_DIM
                              : xb + (long long)rowBase * K_DIM;
    const ushort_t* g[8];
#pragma unroll
    for (int j = 0; j < 8; j++)
        g[j] = src + (long long)(R0 + 4 * j + rowl) * K_DIM + (qb ^ ((4 * j) & 15)) * 8;
    ushort_t* lbase = (isB ? ldsB : ldsA) + R0 * BK;  // wave-uniform

    // ---- fragment read offsets ----
    // Row r = waveR/C + mi*16 + lrow -> r&15 = lrow. Chunk c = kc*4 + quad,
    // stored at (kc*4 ^ quad ^ lrow); ushort offset = that * 8 = sw ^ (kc*32).
    const int sw = (quad ^ lrow) * 8;
    const ushort_t* aP = &ldsA[(waveR + lrow) * BK];
    const ushort_t* bP = &ldsB[(waveC + lrow) * BK];

    float4v acc[4][2] = {};

    for (int k0 = 0; k0 < K_DIM; k0 += BK) {
#pragma unroll
        for (int j = 0; j < 8; j++) {
            async_load16(g[j], lbase + (4 * j) * BK);
            g[j] += BK;
        }
        __syncthreads();

#pragma unroll
        for (int kc = 0; kc < 4; kc++) {
            const int ko = sw ^ (kc * 32);
            short8 af[4], bf[2];
#pragma unroll
            for (int mi = 0; mi < 4; mi++)
                af[mi] = *(const short8*)(aP + mi * 16 * BK + ko);
#pragma unroll
            for (int ni = 0; ni < 2; ni++)
                bf[ni] = *(const short8*)(bP + ni * 16 * BK + ko);
#pragma unroll
            for (int mi = 0; mi < 4; mi++)
#pragma unroll
                for (int ni = 0; ni < 2; ni++)
                    acc[mi][ni] = __builtin_amdgcn_mfma_f32_16x16x32_bf16(
                        af[mi], bf[ni], acc[mi][ni], 0, 0, 0);
        }
        __syncthreads();
    }

    // ---- epilogue: C/D layout col=lane&15, row=quad*4+reg ----
#pragma unroll
    for (int ni = 0; ni < 2; ni++) {
        const int col = colBase + waveC + ni * 16 + lrow;
        const float bv = bias[col];
#pragma unroll
        for (int mi = 0; mi < 4; mi++) {
            const int row0 = rowBase + waveR + mi * 16 + quad * 4;
            float4v v = acc[mi][ni];
#pragma unroll
            for (int i = 0; i < 4; i++)
                out[(long long)(row0 + i) * N_DIM + col] = v[i] + bv;
        }
    }
}

// ---------------- fallback (ws too small): fp32 naive ----------------
__global__ void __launch_bounds__(256) linear_naive(const float* __restrict__ x,
                                                    const float* __restrict__ w,
                                                    const float* __restrict__ bias,
                                                    float* __restrict__ out) {
    __shared__ float xs[K_DIM];
    const int b = blockIdx.y;
    const int o = blockIdx.x * 256 + threadIdx.x;
    for (int k = threadIdx.x; k < K_DIM; k += 256)
        xs[k] = x[(long long)b * K_DIM + k];
    __syncthreads();
    const float4v* wr = (const float4v*)(w + (long long)o * K_DIM);
    float s = 0.f;
    for (int k4 = 0; k4 < K_DIM / 4; k4++) {
        float4v wv = wr[k4];
        float4v xv = *(const float4v*)&xs[k4 * 4];
        s += xv[0] * wv[0] + xv[1] * wv[1] + xv[2] * wv[2] + xv[3] * wv[3];
    }
    out[(long long)b * N_DIM + o] = s + bias[o];
}

extern "C" void kernel_launch(void* const* d_in, const int* in_sizes, int n_in,
                              void* d_out, int out_size, void* d_ws, size_t ws_size,
                              hipStream_t stream) {
    const float* x    = (const float*)d_in[0];   // [4096, 2048]
    const float* w    = (const float*)d_in[1];   // [2048, 2048]
    const float* bias = (const float*)d_in[2];   // [2048]
    float* out = (float*)d_out;                  // [4096, 2048]

    const size_t xElems = (size_t)M_DIM * K_DIM;   // 8388608
    const size_t wElems = (size_t)N_DIM * K_DIM;   // 4194304
    const size_t need = (xElems + wElems) * sizeof(ushort_t);  // ~25.2 MB

    if (ws_size >= need) {
        ushort_t* xb = (ushort_t*)d_ws;
        ushort_t* wb = xb + xElems;
        const int xN8 = (int)(xElems / 8);
        const int totN8 = (int)((xElems + wElems) / 8);
        cvt_both<<<(totN8 + 255) / 256, 256, 0, stream>>>(x, w, (ushort8*)d_ws, xN8, totN8);
        gemm_bf16<<<(M_DIM / 128) * (N_DIM / 128), 512, 0, stream>>>(xb, wb, bias, out);
    } else {
        dim3 grid(N_DIM / 256, M_DIM);
        linear_naive<<<grid, 256, 0, stream>>>(x, w, bias, out);
    }
}